// Round 3
// baseline (146.488 us; speedup 1.0000x reference)
//
#include <hip/hip_runtime.h>
#include <hip/hip_bf16.h>

#define BB 2
#define CC 128
#define HH 48
#define WW 48
#define NN (HH*WW)          // 2304
#define NB 25               // AP bins
#define PB 26               // positives hist bins + spill (only ever gets +0)
#define HST 27              // per-thread hist stride (odd -> 2-way banks max)
#define QT 16               // queries per block
#define MT 64               // m per iteration
#define NTILES (NN/QT)      // 144
#define ITERS (NN/MT)       // 36 (MSPLIT=1: each block owns the full m-range)
#define PSCALE 16777216.0f  // 2^24 fixed point
#define PINV   (1.0f/16777216.0f)

typedef __bf16 bf16x8 __attribute__((ext_vector_type(8)));
typedef float  f32x4  __attribute__((ext_vector_type(4)));
typedef unsigned short u16;
typedef unsigned int   u32;
typedef unsigned long long u64;

static __device__ __forceinline__ u16 f2bf(float x) {
    __hip_bfloat16 h = __float2bfloat16(x);
    return __builtin_bit_cast(u16, h);
}

// Fused producer (round-0 form): blocks [0,144) transpose img1 -> Qt[b][n][c];
// blocks [144,288) bilinear grid-sample img2 -> Dt[b][m][c]. Block 0 zeroes out.
__global__ __launch_bounds__(256)
void k_prep(const float* __restrict__ img1, const float* __restrict__ img2,
            const float* __restrict__ grid, u16* __restrict__ Qt,
            u16* __restrict__ Dt, float* __restrict__ out) {
    int blk = blockIdx.x;
    if (blk == 0 && threadIdx.x == 0) out[0] = 0.0f;
    bool isg = blk >= 144;
    int bb  = isg ? blk - 144 : blk;
    int bm  = (bb >> 3) * 256 + threadIdx.x;   // b*NN + n, 18*256 = 4608
    int cc0 = (bb & 7) * 16;
    int b   = bm / NN;
    int p   = bm - b * NN;
    u16 tmp[16];
    if (!isg) {
        const float* im = img1 + (size_t)b * CC * NN + (size_t)cc0 * NN;
        #pragma unroll
        for (int c = 0; c < 16; ++c) tmp[c] = f2bf(im[(size_t)c * NN + p]);
        uint4* dst = reinterpret_cast<uint4*>(Qt + (size_t)bm * CC + cc0);
        dst[0] = *reinterpret_cast<uint4*>(&tmp[0]);
        dst[1] = *reinterpret_cast<uint4*>(&tmp[8]);
    } else {
        float gx = grid[bm * 2 + 0];
        float gy = grid[bm * 2 + 1];
        float ix = ((gx + 1.0f) * (float)WW - 1.0f) * 0.5f;
        float iy = ((gy + 1.0f) * (float)HH - 1.0f) * 0.5f;
        float x0f = floorf(ix), y0f = floorf(iy);
        float wx1 = ix - x0f, wy1 = iy - y0f;
        float wx0 = 1.0f - wx1, wy0 = 1.0f - wy1;
        int x0 = (int)x0f, y0 = (int)y0f;
        bool xv0 = (x0 >= 0) && (x0 < WW);
        bool xv1 = (x0 + 1 >= 0) && (x0 + 1 < WW);
        bool yv0 = (y0 >= 0) && (y0 < HH);
        bool yv1 = (y0 + 1 >= 0) && (y0 + 1 < HH);
        int x0c = min(max(x0, 0), WW - 1), x1c = min(max(x0 + 1, 0), WW - 1);
        int y0c = min(max(y0, 0), HH - 1), y1c = min(max(y0 + 1, 0), HH - 1);
        float w00 = (xv0 && yv0) ? wx0 * wy0 : 0.0f;
        float w01 = (xv1 && yv0) ? wx1 * wy0 : 0.0f;
        float w10 = (xv0 && yv1) ? wx0 * wy1 : 0.0f;
        float w11 = (xv1 && yv1) ? wx1 * wy1 : 0.0f;
        int p00 = y0c * WW + x0c, p01 = y0c * WW + x1c;
        int p10 = y1c * WW + x0c, p11 = y1c * WW + x1c;
        const float* im = img2 + (size_t)b * CC * NN + (size_t)cc0 * NN;
        #pragma unroll
        for (int c = 0; c < 16; ++c) {
            const float* pl = im + (size_t)c * NN;
            tmp[c] = f2bf(pl[p00] * w00 + pl[p01] * w01 + pl[p10] * w10 + pl[p11] * w11);
        }
        uint4* dst = reinterpret_cast<uint4*>(Dt + (size_t)bm * CC + cc0);
        dst[0] = *reinterpret_cast<uint4*>(&tmp[0]);
        dst[1] = *reinterpret_cast<uint4*>(&tmp[8]);
    }
}

// Fully fused main: each block owns 16 queries x the ENTIRE m-range (36 x 64
// tiles), so the AP + reliability + loss can be finished in-block -> no
// finalize kernel, no partial-hist global traffic. Histogram via per-thread
// u32 fixed-point LDS hists with native ds_add_u32 (fire-and-forget).
// D-tile staging is register-double-buffered: next tile's global loads are in
// flight while MFMA+hist consume the current LDS tile.
__global__ __launch_bounds__(256, 3)
void k_main(const u16* __restrict__ Qt, const u16* __restrict__ Dt,
            const float* __restrict__ rel, float* __restrict__ out) {
    __shared__ u16 Qs[QT * 136];        //  4352 B
    union ShU { u16 Ds[MT * 136]; float red[NB * 16]; };
    __shared__ ShU sh;                  // 17408 B (Ds dead before red)
    __shared__ u32 whist[256 * HST];    // 27648 B  per-thread hists
    __shared__ u32 poshu[QT * PB];      //  1664 B  -> 51072 B, 3 blocks/CU

    int tid  = threadIdx.x;
    int bidx = blockIdx.x;              // b*NTILES + ntile, 288 blocks
    int b     = bidx / NTILES;
    int ntile = bidx - b * NTILES;
    int n0 = ntile * QT;

    #pragma unroll
    for (int i = 0; i < HST; ++i) whist[i * 256 + tid] = 0u;
    for (int i = tid; i < QT * PB; i += 256) poshu[i] = 0u;
    {   // Q tile: 16 rows x 16 uint4
        int row = tid >> 4, col = tid & 15;
        *reinterpret_cast<uint4*>(&Qs[row * 136 + col * 8]) =
            *reinterpret_cast<const uint4*>(Qt + ((size_t)(b * NN + n0 + row)) * CC + col * 8);
    }
    int lane = tid & 63, wave = tid >> 6, quad = lane >> 4, l15 = lane & 15;
    int q  = l15;                       // this lane's query, whole kernel
    int n  = n0 + q;
    int rn = n / WW, cn = n % WW;
    u32* ph = &whist[tid * HST];

    int srow = tid >> 4, scol = tid & 15;   // this thread's staging coords
    const u16* dbase = Dt + (size_t)b * NN * CC + (size_t)scol * 8;

    uint4 pf[4];                        // prefetch regs for tile it=0
    #pragma unroll
    for (int k = 0; k < 4; ++k)
        pf[k] = *reinterpret_cast<const uint4*>(dbase + (size_t)(srow + k * 16) * CC);

    int mb = wave * 16 + quad * 4;      // this thread's first m
    int rm = mb / WW, cm = mb % WW;     // tracked incrementally (+64/iter)

    for (int it = 0; it < ITERS; ++it) {
        __syncthreads();                // prev iter's Ds readers done
        #pragma unroll
        for (int k = 0; k < 4; ++k)     // commit prefetched tile to LDS
            *reinterpret_cast<uint4*>(&sh.Ds[(srow + k * 16) * 136 + scol * 8]) = pf[k];
        __syncthreads();
        if (it + 1 < ITERS) {           // launch next tile's loads (in flight
            int m0n = (it + 1) * MT;    //  under MFMA + hist below)
            #pragma unroll
            for (int k = 0; k < 4; ++k)
                pf[k] = *reinterpret_cast<const uint4*>(dbase + (size_t)(m0n + srow + k * 16) * CC);
        }

        f32x4 acc = {0.f, 0.f, 0.f, 0.f};
        #pragma unroll
        for (int kc = 0; kc < 4; ++kc) {
            // A = D rows (M dim = m), B = Q rows (N dim = q) -> C[m][q]
            bf16x8 av = *reinterpret_cast<const bf16x8*>(&sh.Ds[(wave * 16 + l15) * 136 + kc * 32 + quad * 8]);
            bf16x8 bv = *reinterpret_cast<const bf16x8*>(&Qs[l15 * 136 + kc * 32 + quad * 8]);
            acc = __builtin_amdgcn_mfma_f32_16x16x32_bf16(av, bv, acc, 0, 0, 0);
        }

        #pragma unroll
        for (int i = 0; i < 4; ++i) {
            float t  = __builtin_amdgcn_fmed3f(fmaf(-12.0f, acc[i], 12.0f), 0.0f, 24.0f);
            float cf = floorf(t);
            float f  = t - cf;
            int   c0 = (int)cf;         // [0,24]; c0==24 -> f==0 -> spill +0
            u32 w1 = (u32)(fmaf(f, PSCALE, 0.5f));
            u32 w0 = 16777216u - w1;
            atomicAdd(&ph[c0],     w0); // native ds_add_u32, no readback
            atomicAdd(&ph[c0 + 1], w1);
            int ci = cm + i, ri = rm;   // col may wrap once (i<=3)
            if (ci >= WW) { ci -= WW; ++ri; }
            int dr = rn - ri, dc = cn - ci;
            if ((unsigned)(dr + 4) <= 8u && (unsigned)(dc + 4) <= 8u) {
                atomicAdd(&poshu[q * PB + c0],     w0);
                atomicAdd(&poshu[q * PB + c0 + 1], w1);
            }
        }
        rm += 1; cm += 16;              // mb += 64 == +1 row +16 cols
        if (cm >= WW) { cm -= WW; ++rm; }
    }
    __syncthreads();                    // Ds dead from here; red aliases it

    // merge the 16 per-thread hists of each query (u64 exact), -> LDS red
    for (int idx = tid; idx < NB * QT; idx += 256) {
        int qq = idx & 15, c = idx >> 4;
        u64 s = 0;
        #pragma unroll
        for (int j = 0; j < 16; ++j) s += (u64)whist[(j * 16 + qq) * HST + c];
        sh.red[c * 16 + qq] = (float)s * PINV;
    }
    __syncthreads();

    // in-block finalize: AP + reliability + loss for this block's 16 queries
    float loss = 0.0f;
    if (tid < QT) {
        int qq = tid;
        float cumr = 0.f, cumn = 0.f, apn = 0.f, totr = 0.f;
        #pragma unroll
        for (int c = 0; c < NB; ++c) {
            float a = sh.red[c * 16 + qq];
            float r = (float)poshu[qq * PB + c] * PINV;
            cumr += r; cumn += a;
            apn  += (cumr / (1e-16f + cumn)) * r;
            totr += r;
        }
        float ap = apn / totr;          // totr >= 1 (self-match)
        float rl = rel[b * NN + n0 + qq];
        loss = 1.0f - (ap * rl + 0.5f * (1.0f - rl));
    }
    if (wave == 0) {                    // all 64 lanes active -> shfl is safe
        #pragma unroll
        for (int off = 8; off > 0; off >>= 1) loss += __shfl_down(loss, off, 64);
        if (tid == 0) atomicAdd(out, loss * (1.0f / (float)(BB * NN)));
    }
}

extern "C" void kernel_launch(void* const* d_in, const int* in_sizes, int n_in,
                              void* d_out, int out_size, void* d_ws, size_t ws_size,
                              hipStream_t stream) {
    const float* img1 = (const float*)d_in[0];
    const float* img2 = (const float*)d_in[1];
    const float* rel  = (const float*)d_in[2];
    const float* grid = (const float*)d_in[3];

    char* ws = (char*)d_ws;
    const size_t qt_bytes = (size_t)BB * NN * CC * sizeof(u16);   // 1.18 MB
    u16* Qt = (u16*)ws;
    u16* Dt = (u16*)(ws + qt_bytes);

    k_prep<<<288, 256, 0, stream>>>(img1, img2, grid, Qt, Dt, (float*)d_out);
    k_main<<<BB * NTILES, 256, 0, stream>>>(Qt, Dt, rel, (float*)d_out);
}

// Round 4
// 117.552 us; speedup vs baseline: 1.2461x; 1.2461x over previous
//
#include <hip/hip_runtime.h>
#include <hip/hip_bf16.h>

#define BB 2
#define CC 128
#define HH 48
#define WW 48
#define NN (HH*WW)          // 2304
#define NB 25               // AP bins
#define PB 26               // positives bins + spill (spill only ever gets +0)
#define HST 27              // hist stride (odd -> 2 lanes/bank = free)
#define HSH 64              // hists per block, shared by tid&63 (atomic-safe)
#define QT 16               // queries per block
#define MT 64               // m per iteration
#define MSPLIT 4            // m-range split -> 1152 main blocks
#define NTILES (NN/QT)      // 144
#define ITERS (NN/MSPLIT/MT)  // 9
#define GQ 51               // u64 per query in G: 25 hist + 26 positives
#define GT (QT*GQ)          // 816 u64 per tile
#define PSCALE 16777216.0f  // 2^24 fixed point
#define PINV   (1.0f/16777216.0f)

typedef __bf16 bf16x8 __attribute__((ext_vector_type(8)));
typedef float  f32x4  __attribute__((ext_vector_type(4)));
typedef unsigned short u16;
typedef unsigned int   u32;
typedef unsigned long long u64;

static __device__ __forceinline__ u16 f2bf(float x) {
    __hip_bfloat16 h = __float2bfloat16(x);
    return __builtin_bit_cast(u16, h);
}

// Producer, 576 blocks: [0,288) transpose img1 -> Qt[b][n][c] (8-ch chunks);
// [288,576) bilinear grid-sample img2 -> Dt[b][m][c] (8-ch chunks).
// Also zeroes G+cnt (workspace is poisoned by the harness) and d_out.
__global__ __launch_bounds__(256)
void k_prep(const float* __restrict__ img1, const float* __restrict__ img2,
            const float* __restrict__ grid, u16* __restrict__ Qt,
            u16* __restrict__ Dt, u64* __restrict__ G, float* __restrict__ out) {
    int blk = blockIdx.x, tid = threadIdx.x;
    // zero G (2*144*816 u64) + cnt (288 u32) = 1881216 B = 117576 uint4 exactly
    int zi = blk * 256 + tid;
    if (zi < 117576) reinterpret_cast<uint4*>(G)[zi] = make_uint4(0u, 0u, 0u, 0u);
    if (blk == 0 && tid == 0) out[0] = 0.0f;

    if (blk < 288) {        // transpose half
        int bm  = (blk >> 4) * 256 + tid;      // b*NN + n  in [0,4608)
        int cc0 = (blk & 15) * 8;
        int b   = bm / NN;
        int p   = bm - b * NN;
        const float* im = img1 + (size_t)b * CC * NN + (size_t)cc0 * NN;
        u16 tmp[8];
        #pragma unroll
        for (int c = 0; c < 8; ++c) tmp[c] = f2bf(im[(size_t)c * NN + p]);
        *reinterpret_cast<uint4*>(Qt + (size_t)bm * CC + cc0) =
            *reinterpret_cast<uint4*>(&tmp[0]);
    } else {                // gather half
        int gb  = blk - 288;
        int bm  = (gb >> 4) * 256 + tid;       // b*NN + m
        int cc0 = (gb & 15) * 8;
        int b   = bm / NN;
        float gx = grid[bm * 2 + 0];
        float gy = grid[bm * 2 + 1];
        float ix = ((gx + 1.0f) * (float)WW - 1.0f) * 0.5f;
        float iy = ((gy + 1.0f) * (float)HH - 1.0f) * 0.5f;
        float x0f = floorf(ix), y0f = floorf(iy);
        float wx1 = ix - x0f, wy1 = iy - y0f;
        float wx0 = 1.0f - wx1, wy0 = 1.0f - wy1;
        int x0 = (int)x0f, y0 = (int)y0f;
        bool xv0 = (x0 >= 0) && (x0 < WW);
        bool xv1 = (x0 + 1 >= 0) && (x0 + 1 < WW);
        bool yv0 = (y0 >= 0) && (y0 < HH);
        bool yv1 = (y0 + 1 >= 0) && (y0 + 1 < HH);
        int x0c = min(max(x0, 0), WW - 1), x1c = min(max(x0 + 1, 0), WW - 1);
        int y0c = min(max(y0, 0), HH - 1), y1c = min(max(y0 + 1, 0), HH - 1);
        float w00 = (xv0 && yv0) ? wx0 * wy0 : 0.0f;
        float w01 = (xv1 && yv0) ? wx1 * wy0 : 0.0f;
        float w10 = (xv0 && yv1) ? wx0 * wy1 : 0.0f;
        float w11 = (xv1 && yv1) ? wx1 * wy1 : 0.0f;
        int p00 = y0c * WW + x0c, p01 = y0c * WW + x1c;
        int p10 = y1c * WW + x0c, p11 = y1c * WW + x1c;
        const float* im = img2 + (size_t)b * CC * NN + (size_t)cc0 * NN;
        u16 tmp[8];
        #pragma unroll
        for (int c = 0; c < 8; ++c) {
            const float* pl = im + (size_t)c * NN;
            tmp[c] = f2bf(pl[p00] * w00 + pl[p01] * w01 + pl[p10] * w10 + pl[p11] * w11);
        }
        *reinterpret_cast<uint4*>(Dt + (size_t)bm * CC + cc0) =
            *reinterpret_cast<uint4*>(&tmp[0]);
    }
}

// Main, 1152 blocks: NO LDS staging, NO in-loop barriers. Q-frags live in
// registers for the whole kernel; D-frags stream directly from L2-resident Dt.
// Hist: u32 fixed-point ds_add (fire-and-forget) into 64 lane-owned hists
// (shared by tid&63 across the 4 waves -> no intra-wave address aliasing).
// Cross-split merge: u64 device-scope global atomics; the last block of each
// tile (per-tile counter) reads the 816 u64s back via atomicAdd(p,0) -- an RMW
// at the coherence point, immune to cross-XCD L2 staleness -- and finishes
// AP + reliability + loss in-block. No third kernel.
__global__ __launch_bounds__(256, 5)
void k_main(const u16* __restrict__ Qt, const u16* __restrict__ Dt,
            const float* __restrict__ rel, u64* __restrict__ G,
            u32* __restrict__ cnt, float* __restrict__ out) {
    __shared__ u32 whist[HSH * HST];    // 6912 B
    __shared__ u32 poshu[QT * PB];      // 1664 B
    __shared__ u64 red[GT];             // 6528 B readback buffer
    __shared__ int lastflag;

    int tid  = threadIdx.x;
    int bidx = blockIdx.x;              // ((b*144 + ntile)*4 + ms)
    int b     = bidx / (NTILES * MSPLIT);
    int rem   = bidx % (NTILES * MSPLIT);
    int ntile = rem / MSPLIT;
    int ms    = rem % MSPLIT;
    int n0 = ntile * QT;

    for (int i = tid; i < HSH * HST; i += 256) whist[i] = 0u;
    for (int i = tid; i < QT * PB; i += 256) poshu[i] = 0u;

    int lane = tid & 63, wave = tid >> 6, quad = lane >> 4, l15 = lane & 15;
    int q  = l15;                       // this lane's query, whole kernel
    int n  = n0 + q;
    int rn = n / WW, cn = n % WW;
    u32* ph = &whist[(tid & 63) * HST];

    // Q fragments: one row per lane, all 4 k-slices, held in registers
    const u16* qrow = Qt + (size_t)(b * NN + n0 + l15) * CC + quad * 8;
    bf16x8 bv0 = *reinterpret_cast<const bf16x8*>(qrow);
    bf16x8 bv1 = *reinterpret_cast<const bf16x8*>(qrow + 32);
    bf16x8 bv2 = *reinterpret_cast<const bf16x8*>(qrow + 64);
    bf16x8 bv3 = *reinterpret_cast<const bf16x8*>(qrow + 96);

    int mstart = ms * (NN / MSPLIT);
    const u16* drow = Dt + (size_t)(b * NN + mstart + wave * 16 + l15) * CC + quad * 8;

    int mb = mstart + wave * 16 + quad * 4;   // this thread's first m
    int rm = mb / WW, cm = mb % WW;           // tracked incrementally (+64/iter)

    __syncthreads();                    // hist init visible

    #pragma unroll 3
    for (int it = 0; it < ITERS; ++it) {
        const u16* dr = drow + (size_t)it * MT * CC;
        f32x4 acc = {0.f, 0.f, 0.f, 0.f};
        acc = __builtin_amdgcn_mfma_f32_16x16x32_bf16(
                  *reinterpret_cast<const bf16x8*>(dr),       bv0, acc, 0, 0, 0);
        acc = __builtin_amdgcn_mfma_f32_16x16x32_bf16(
                  *reinterpret_cast<const bf16x8*>(dr + 32),  bv1, acc, 0, 0, 0);
        acc = __builtin_amdgcn_mfma_f32_16x16x32_bf16(
                  *reinterpret_cast<const bf16x8*>(dr + 64),  bv2, acc, 0, 0, 0);
        acc = __builtin_amdgcn_mfma_f32_16x16x32_bf16(
                  *reinterpret_cast<const bf16x8*>(dr + 96),  bv3, acc, 0, 0, 0);

        #pragma unroll
        for (int i = 0; i < 4; ++i) {
            float t  = __builtin_amdgcn_fmed3f(fmaf(-12.0f, acc[i], 12.0f), 0.0f, 24.0f);
            float cf = floorf(t);
            float f  = t - cf;
            int   c0 = (int)cf;         // [0,24]; c0==24 -> f==0 -> spill +0
            u32 w1 = (u32)(fmaf(f, PSCALE, 0.5f));
            u32 w0 = 16777216u - w1;
            atomicAdd(&ph[c0],     w0); // native ds_add_u32, no readback
            atomicAdd(&ph[c0 + 1], w1);
            int ci = cm + i, ri = rm;   // col may wrap once (i<=3)
            if (ci >= WW) { ci -= WW; ++ri; }
            int dr2 = rn - ri, dc = cn - ci;
            if ((unsigned)(dr2 + 4) <= 8u && (unsigned)(dc + 4) <= 8u) {
                atomicAdd(&poshu[q * PB + c0],     w0);
                atomicAdd(&poshu[q * PB + c0 + 1], w1);
            }
        }
        rm += 1; cm += 16;              // m += 64 == +1 row +16 cols
        if (cm >= WW) { cm -= WW; ++rm; }
    }
    __syncthreads();                    // all ds_adds done

    // merge this block's hists -> global u64 tile hist (device-scope atomics)
    u64* Gt = G + (size_t)(b * NTILES + ntile) * GT;
    for (int idx = tid; idx < NB * QT; idx += 256) {   // 400 all-hist cells
        int qq = idx & 15, c = idx >> 4;
        u64 s = (u64)whist[(qq)      * HST + c] + (u64)whist[(16 + qq) * HST + c]
              + (u64)whist[(32 + qq) * HST + c] + (u64)whist[(48 + qq) * HST + c];
        atomicAdd(&Gt[qq * GQ + c], s);
    }
    for (int idx = tid; idx < PB * QT; idx += 256) {   // 416 positives cells
        int qq = idx & 15, c = idx >> 4;
        atomicAdd(&Gt[qq * GQ + NB + c], (u64)poshu[qq * PB + c]);
    }
    __syncthreads();                    // barrier drains vmcnt -> atomics acked
    if (tid == 0) {
        __threadfence();                // belt-and-suspenders release
        u32 old = atomicAdd(&cnt[b * NTILES + ntile], 1u);
        lastflag = (old == MSPLIT - 1);
    }
    __syncthreads();
    if (!lastflag) return;

    // last block of this tile: read back full tile hist via atomic RMW
    for (int idx = tid; idx < GT; idx += 256)
        red[idx] = atomicAdd(&Gt[idx], 0ull);
    __syncthreads();

    float loss = 0.0f;
    if (tid < QT) {
        int qq = tid;
        float cumr = 0.f, cumn = 0.f, apn = 0.f, totr = 0.f;
        #pragma unroll
        for (int c = 0; c < NB; ++c) {
            float a = (float)red[qq * GQ + c]      * PINV;
            float r = (float)red[qq * GQ + NB + c] * PINV;
            cumr += r; cumn += a;
            apn  += (cumr / (1e-16f + cumn)) * r;
            totr += r;
        }
        float ap = apn / totr;          // totr >= 1 (self-match)
        float rl = rel[b * NN + n0 + qq];
        loss = 1.0f - (ap * rl + 0.5f * (1.0f - rl));
    }
    if (wave == 0) {                    // lanes >=16 carry 0
        #pragma unroll
        for (int off = 8; off > 0; off >>= 1) loss += __shfl_down(loss, off, 64);
        if (tid == 0) atomicAdd(out, loss * (1.0f / (float)(BB * NN)));
    }
}

extern "C" void kernel_launch(void* const* d_in, const int* in_sizes, int n_in,
                              void* d_out, int out_size, void* d_ws, size_t ws_size,
                              hipStream_t stream) {
    const float* img1 = (const float*)d_in[0];
    const float* img2 = (const float*)d_in[1];
    const float* rel  = (const float*)d_in[2];
    const float* grid = (const float*)d_in[3];

    char* ws = (char*)d_ws;
    const size_t qt_bytes = (size_t)BB * NN * CC * sizeof(u16);   // 1.18 MB
    const size_t g_bytes  = (size_t)BB * NTILES * GT * sizeof(u64);
    u16* Qt  = (u16*)ws;
    u16* Dt  = (u16*)(ws + qt_bytes);
    u64* G   = (u64*)(ws + 2 * qt_bytes);
    u32* cnt = (u32*)(ws + 2 * qt_bytes + g_bytes);   // contiguous after G

    k_prep<<<576, 256, 0, stream>>>(img1, img2, grid, Qt, Dt, G, (float*)d_out);
    k_main<<<BB * NTILES * MSPLIT, 256, 0, stream>>>(Qt, Dt, rel, G, cnt, (float*)d_out);
}

// Round 5
// 104.076 us; speedup vs baseline: 1.4075x; 1.1295x over previous
//
#include <hip/hip_runtime.h>
#include <hip/hip_bf16.h>

#define BB 2
#define CC 128
#define HH 48
#define WW 48
#define NN (HH*WW)          // 2304
#define NB 25               // AP bins
#define PB 26               // positives bins + spill (spill only ever gets +0)
#define HST 27              // hist stride (odd -> 2 lanes/bank = free)
#define NHIST 256           // hists per block (shared by tid and tid+256)
#define QT 16               // queries per block
#define WAVES 8             // waves per block (512 threads)
#define MSLICE (NN/WAVES)   // 288 m-rows per wave
#define ITERW (MSLICE/16)   // 18 iterations per wave
#define NTILES (NN/QT)      // 144
#define PSCALE 16777216.0f  // 2^24 fixed point
#define PINV   (1.0f/16777216.0f)

typedef __bf16 bf16x8 __attribute__((ext_vector_type(8)));
typedef float  f32x4  __attribute__((ext_vector_type(4)));
typedef unsigned short u16;
typedef unsigned int   u32;
typedef unsigned long long u64;

static __device__ __forceinline__ u16 f2bf(float x) {
    __hip_bfloat16 h = __float2bfloat16(x);
    return __builtin_bit_cast(u16, h);
}

// Producer, 576 blocks: [0,288) transpose img1 -> Qt[b][n][c] (8-ch chunks);
// [288,576) bilinear grid-sample img2 -> Dt[b][m][c] (8-ch chunks).
__global__ __launch_bounds__(256)
void k_prep(const float* __restrict__ img1, const float* __restrict__ img2,
            const float* __restrict__ grid, u16* __restrict__ Qt,
            u16* __restrict__ Dt, float* __restrict__ out) {
    int blk = blockIdx.x, tid = threadIdx.x;
    if (blk == 0 && tid == 0) out[0] = 0.0f;

    if (blk < 288) {        // transpose half
        int bm  = (blk >> 4) * 256 + tid;      // b*NN + n  in [0,4608)
        int cc0 = (blk & 15) * 8;
        int b   = bm / NN;
        int p   = bm - b * NN;
        const float* im = img1 + (size_t)b * CC * NN + (size_t)cc0 * NN;
        u16 tmp[8];
        #pragma unroll
        for (int c = 0; c < 8; ++c) tmp[c] = f2bf(im[(size_t)c * NN + p]);
        *reinterpret_cast<uint4*>(Qt + (size_t)bm * CC + cc0) =
            *reinterpret_cast<uint4*>(&tmp[0]);
    } else {                // gather half
        int gb  = blk - 288;
        int bm  = (gb >> 4) * 256 + tid;       // b*NN + m
        int cc0 = (gb & 15) * 8;
        int b   = bm / NN;
        float gx = grid[bm * 2 + 0];
        float gy = grid[bm * 2 + 1];
        float ix = ((gx + 1.0f) * (float)WW - 1.0f) * 0.5f;
        float iy = ((gy + 1.0f) * (float)HH - 1.0f) * 0.5f;
        float x0f = floorf(ix), y0f = floorf(iy);
        float wx1 = ix - x0f, wy1 = iy - y0f;
        float wx0 = 1.0f - wx1, wy0 = 1.0f - wy1;
        int x0 = (int)x0f, y0 = (int)y0f;
        bool xv0 = (x0 >= 0) && (x0 < WW);
        bool xv1 = (x0 + 1 >= 0) && (x0 + 1 < WW);
        bool yv0 = (y0 >= 0) && (y0 < HH);
        bool yv1 = (y0 + 1 >= 0) && (y0 + 1 < HH);
        int x0c = min(max(x0, 0), WW - 1), x1c = min(max(x0 + 1, 0), WW - 1);
        int y0c = min(max(y0, 0), HH - 1), y1c = min(max(y0 + 1, 0), HH - 1);
        float w00 = (xv0 && yv0) ? wx0 * wy0 : 0.0f;
        float w01 = (xv1 && yv0) ? wx1 * wy0 : 0.0f;
        float w10 = (xv0 && yv1) ? wx0 * wy1 : 0.0f;
        float w11 = (xv1 && yv1) ? wx1 * wy1 : 0.0f;
        int p00 = y0c * WW + x0c, p01 = y0c * WW + x1c;
        int p10 = y1c * WW + x0c, p11 = y1c * WW + x1c;
        const float* im = img2 + (size_t)b * CC * NN + (size_t)cc0 * NN;
        u16 tmp[8];
        #pragma unroll
        for (int c = 0; c < 8; ++c) {
            const float* pl = im + (size_t)c * NN;
            tmp[c] = f2bf(pl[p00] * w00 + pl[p01] * w01 + pl[p10] * w10 + pl[p11] * w11);
        }
        *reinterpret_cast<uint4*>(Dt + (size_t)bm * CC + cc0) =
            *reinterpret_cast<uint4*>(&tmp[0]);
    }
}

// Main, 288 blocks x 512 threads: fully fused, ZERO global atomics except one
// f32 add of the block's loss. The m-range split is INTRA-block: wave w owns
// m-rows [w*288,(w+1)*288) -> 18 iters of the lean loop (register Q-frags,
// D-frags streamed straight from L2-resident Dt, no in-loop barriers).
// Hist: u32 fixed-point ds_add fire-and-forget into 256 hists (hist = tid&255,
// shared by exactly 2 threads; per-cell max 144*2^24 < 2^32). One barrier,
// LDS merge, in-block AP + reliability + loss, single atomicAdd(out).
__global__ __launch_bounds__(512)
void k_main(const u16* __restrict__ Qt, const u16* __restrict__ Dt,
            const float* __restrict__ rel, float* __restrict__ out) {
    __shared__ u32   whist[NHIST * HST];  // 27648 B
    __shared__ u32   poshu[QT * PB];      //  1664 B
    __shared__ float red[NB * QT];        //  1600 B  -> ~30.9 KB total

    int tid  = threadIdx.x;
    int bidx = blockIdx.x;              // b*NTILES + ntile
    int b     = bidx / NTILES;
    int ntile = bidx - b * NTILES;
    int n0 = ntile * QT;

    for (int i = tid; i < NHIST * HST; i += 512) whist[i] = 0u;
    for (int i = tid; i < QT * PB; i += 512) poshu[i] = 0u;

    int lane = tid & 63, wave = tid >> 6, quad = lane >> 4, l15 = lane & 15;
    int q  = l15;                       // this lane's query, whole kernel
    int n  = n0 + q;
    int rn = n / WW, cn = n % WW;
    u32* ph = &whist[(tid & 255) * HST];

    // Q fragments: one row per lane, all 4 k-slices, held in registers
    const u16* qrow = Qt + (size_t)(b * NN + n0 + l15) * CC + quad * 8;
    bf16x8 bv0 = *reinterpret_cast<const bf16x8*>(qrow);
    bf16x8 bv1 = *reinterpret_cast<const bf16x8*>(qrow + 32);
    bf16x8 bv2 = *reinterpret_cast<const bf16x8*>(qrow + 64);
    bf16x8 bv3 = *reinterpret_cast<const bf16x8*>(qrow + 96);

    const u16* drow = Dt + (size_t)(b * NN + wave * MSLICE + l15) * CC + quad * 8;

    int mb = wave * MSLICE + quad * 4;  // this thread's first m
    int rm = mb / WW, cm = mb % WW;     // tracked incrementally (+16/iter)

    __syncthreads();                    // hist init visible to sharing threads

    #pragma unroll 2
    for (int it = 0; it < ITERW; ++it) {
        const u16* dr = drow + (size_t)it * 16 * CC;
        f32x4 acc = {0.f, 0.f, 0.f, 0.f};
        acc = __builtin_amdgcn_mfma_f32_16x16x32_bf16(
                  *reinterpret_cast<const bf16x8*>(dr),       bv0, acc, 0, 0, 0);
        acc = __builtin_amdgcn_mfma_f32_16x16x32_bf16(
                  *reinterpret_cast<const bf16x8*>(dr + 32),  bv1, acc, 0, 0, 0);
        acc = __builtin_amdgcn_mfma_f32_16x16x32_bf16(
                  *reinterpret_cast<const bf16x8*>(dr + 64),  bv2, acc, 0, 0, 0);
        acc = __builtin_amdgcn_mfma_f32_16x16x32_bf16(
                  *reinterpret_cast<const bf16x8*>(dr + 96),  bv3, acc, 0, 0, 0);

        #pragma unroll
        for (int i = 0; i < 4; ++i) {
            float t  = __builtin_amdgcn_fmed3f(fmaf(-12.0f, acc[i], 12.0f), 0.0f, 24.0f);
            float cf = floorf(t);
            float f  = t - cf;
            int   c0 = (int)cf;         // [0,24]; c0==24 -> f==0 -> spill +0
            u32 w1 = (u32)(fmaf(f, PSCALE, 0.5f));
            u32 w0 = 16777216u - w1;
            atomicAdd(&ph[c0],     w0); // native ds_add_u32, no readback
            atomicAdd(&ph[c0 + 1], w1);
            int ci = cm + i, ri = rm;   // col may wrap once (i<=3)
            if (ci >= WW) { ci -= WW; ++ri; }
            int dr2 = rn - ri, dc = cn - ci;
            if ((unsigned)(dr2 + 4) <= 8u && (unsigned)(dc + 4) <= 8u) {
                atomicAdd(&poshu[q * PB + c0],     w0);
                atomicAdd(&poshu[q * PB + c0 + 1], w1);
            }
        }
        cm += 16;                       // m += 16
        if (cm >= WW) { cm -= WW; ++rm; }
    }
    __syncthreads();                    // all ds_adds done

    // merge: hist h serves query h&15; sum the 16 hists per (q,c) (u64 exact)
    for (int idx = tid; idx < NB * QT; idx += 512) {
        int qq = idx & 15, c = idx >> 4;
        u64 s = 0;
        #pragma unroll
        for (int j = 0; j < 16; ++j) s += (u64)whist[(j * 16 + qq) * HST + c];
        red[c * 16 + qq] = (float)s * PINV;
    }
    __syncthreads();

    // in-block finalize: AP + reliability + loss for this block's 16 queries
    float loss = 0.0f;
    if (tid < QT) {
        int qq = tid;
        float cumr = 0.f, cumn = 0.f, apn = 0.f, totr = 0.f;
        #pragma unroll
        for (int c = 0; c < NB; ++c) {
            float a = red[c * 16 + qq];
            float r = (float)poshu[qq * PB + c] * PINV;
            cumr += r; cumn += a;
            apn  += (cumr / (1e-16f + cumn)) * r;
            totr += r;
        }
        float ap = apn / totr;          // totr >= 1 (self-match)
        float rl = rel[b * NN + n0 + qq];
        loss = 1.0f - (ap * rl + 0.5f * (1.0f - rl));
    }
    if (wave == 0) {                    // lanes >=16 carry 0
        #pragma unroll
        for (int off = 8; off > 0; off >>= 1) loss += __shfl_down(loss, off, 64);
        if (tid == 0) atomicAdd(out, loss * (1.0f / (float)(BB * NN)));
    }
}

extern "C" void kernel_launch(void* const* d_in, const int* in_sizes, int n_in,
                              void* d_out, int out_size, void* d_ws, size_t ws_size,
                              hipStream_t stream) {
    const float* img1 = (const float*)d_in[0];
    const float* img2 = (const float*)d_in[1];
    const float* rel  = (const float*)d_in[2];
    const float* grid = (const float*)d_in[3];

    char* ws = (char*)d_ws;
    const size_t qt_bytes = (size_t)BB * NN * CC * sizeof(u16);   // 1.18 MB
    u16* Qt = (u16*)ws;
    u16* Dt = (u16*)(ws + qt_bytes);

    k_prep<<<576, 256, 0, stream>>>(img1, img2, grid, Qt, Dt, (float*)d_out);
    k_main<<<BB * NTILES, 512, 0, stream>>>(Qt, Dt, rel, (float*)d_out);
}